// Round 3
// baseline (2701.105 us; speedup 1.0000x reference)
//
#include <hip/hip_runtime.h>

#define TT 512
#define BB 64
#define EE 256
#define HH 512
#define NWG 64
#define THREADS 256
#define BBHH (BB * HH)

typedef unsigned short u16;
typedef unsigned int u32;
typedef unsigned long long u64;
typedef __attribute__((ext_vector_type(8))) short bh8;
typedef __attribute__((ext_vector_type(4))) float f32x4;

__device__ __forceinline__ u16 f2b(float f) {
  union { float f; u32 u; } v; v.f = f;
  return (u16)((v.u + 0x7fffu + ((v.u >> 16) & 1u)) >> 16);
}
__device__ __forceinline__ float b2f(u16 b) {
  union { u32 u; float f; } v; v.u = ((u32)b) << 16; return v.f;
}
__device__ __forceinline__ float sigm(float x) { return 1.f / (1.f + __expf(-x)); }
__device__ __forceinline__ float tanh_f(float x) {
  float e = __expf(2.f * x);
  return 1.f - 2.f / (e + 1.f);
}

// ws layout: [flags 4KB][xe 16MB][hbuf: 513*64KB (cached) or 2*64KB (parity)]
// flags: u32 flags[4][64] — group v's 64 flags packed in 256B (4 lines/poll).

// ---- kernel 0: zero flags + hbuf[0..1] ----
__global__ void k_init(u32* __restrict__ flags, u32* __restrict__ hb) {
  const int gid = blockIdx.x * 256 + threadIdx.x;   // 128 blocks -> 32768
  if (gid < 1024) flags[gid] = 0u;
  if (gid < 32768) hb[gid] = 0u;                    // 128 KB
}

// ---- kernel 1: xe[t][b][e] = bf16(emb[x[t,b]][e]) ----
__global__ __launch_bounds__(256) void k_embed(const int* __restrict__ x,
    const float* __restrict__ emb, u16* __restrict__ xe)
{
  const int gid = blockIdx.x * 256 + threadIdx.x;  // TT*BB*EE/8 threads
  const int tb  = gid >> 5;
  const int e0  = (gid & 31) << 3;
  const int tok = x[tb];
  const float4* s = (const float4*)(emb + (size_t)tok * EE + e0);
  float4 a = s[0], b = s[1];
  u16 o[8] = { f2b(a.x), f2b(a.y), f2b(a.z), f2b(a.w),
               f2b(b.x), f2b(b.y), f2b(b.z), f2b(b.w) };
  *(uint4*)(xe + (size_t)tb * EE + e0) = *(uint4*)o;
}

// ---- kernel 2: persistent gate-partitioned LSTM ----
// WG w owns hidden units [8w,8w+8) -> 32 gate rows = 2 MFMA N-tiles.
// Wave v owns batch rows [16v,16v+16): 4 independent sync groups of 64 waves.
// CACHED: h in write-once per-step buffers; stores write-through (sc0sc1) to IF,
// reads are NORMAL cached loads (safe: address written once, read only after
// flag; XCD L2 shares the fill across its ~8 WGs). Batch rows are independent
// in the GEMM, so frozen rows reading stale/poison bytes is harmless.
template<bool CACHED>
__global__ __launch_bounds__(THREADS, 1) void k_lstm(
    const float* __restrict__ Whh, const float* __restrict__ Wih,
    const float* __restrict__ bih, const float* __restrict__ bhh,
    const u16* __restrict__ xe, const int* __restrict__ xlen,
    u16* __restrict__ hbuf, u32* __restrict__ flags)
{
  __shared__ u16 lWhh[32 * HH];   // 32 KB, bf16, XOR-swizzled rows
  __shared__ u16 lWih[32 * EE];   // 16 KB

  const int wg   = blockIdx.x;
  const int tid  = threadIdx.x;
  const int wave = tid >> 6;
  const int lane = tid & 63;
  const int n16  = lane & 15;
  const int grp  = lane >> 4;

  // ---- stage weight slices (f32 -> bf16) into LDS, swizzle byte ^= (row&7)<<4
  #pragma unroll
  for (int it = 0; it < 8; ++it) {
    int idx = it * THREADS + tid;
    int n   = idx >> 6;
    int c0  = (idx & 63) << 3;
    int grow = (n >> 3) * HH + wg * 8 + (n & 7);
    const float* s = Whh + (size_t)grow * HH + c0;
    u16 tmp[8];
    #pragma unroll
    for (int j = 0; j < 8; ++j) tmp[j] = f2b(s[j]);
    *(uint4*)((char*)lWhh + (u32)(n * 1024 + ((c0 << 1) ^ ((n & 7) << 4)))) = *(uint4*)tmp;
  }
  #pragma unroll
  for (int it = 0; it < 4; ++it) {
    int idx = it * THREADS + tid;
    int n   = idx >> 5;
    int c0  = (idx & 31) << 3;
    int grow = (n >> 3) * HH + wg * 8 + (n & 7);
    const float* s = Wih + (size_t)grow * EE + c0;
    u16 tmp[8];
    #pragma unroll
    for (int j = 0; j < 8; ++j) tmp[j] = f2b(s[j]);
    *(uint4*)((char*)lWih + (u32)(n * 512 + ((c0 << 1) ^ ((n & 7) << 4)))) = *(uint4*)tmp;
  }

  // bias sums for this lane's two gate rows (tile0: i/f, tile1: g/o)
  const int r0 = (n16 < 8) ? (wg * 8 + n16) : (HH + wg * 8 + (n16 - 8));
  const int r1 = (n16 < 8) ? (2 * HH + wg * 8 + n16) : (3 * HH + wg * 8 + (n16 - 8));
  const float bs0 = bih[r0] + bhh[r0];
  const float bs1 = bih[r1] + bhh[r1];

  int   lenr[4];
  int   mrow[4];
  float cst[4] = {0.f, 0.f, 0.f, 0.f};
  float hst[4] = {0.f, 0.f, 0.f, 0.f};
  #pragma unroll
  for (int r = 0; r < 4; ++r) { mrow[r] = wave * 16 + grp * 4 + r; lenr[r] = xlen[mrow[r]]; }
  int wmax = lenr[0];
  #pragma unroll
  for (int r = 1; r < 4; ++r) wmax = max(wmax, lenr[r]);
  #pragma unroll
  for (int off = 1; off < 64; off <<= 1) wmax = max(wmax, __shfl_xor(wmax, off));

  const int  arow = wave * 16 + n16;            // A-fragment batch row
  const u32  swz  = (u32)((n16 & 7) << 4);
  const char* pWhh0 = (const char*)lWhh + n16 * 1024;
  const char* pWhh1 = (const char*)lWhh + (16 + n16) * 1024;
  const char* pWih0 = (const char*)lWih + n16 * 512;
  const char* pWih1 = (const char*)lWih + (16 + n16) * 512;

  u32* myf = flags + wave * 64 + wg;            // this wave's flag
  u32* pf  = flags + wave * 64 + lane;          // flag this lane polls (256B/grp)

  __syncthreads();   // weights staged (only barrier in the kernel)

  // prologue: prefetch xe A-fragments for t=0
  bh8 xf[8];
  {
    const u16* px = xe + (size_t)arow * EE + grp * 8;
    #pragma unroll
    for (int k = 0; k < 8; ++k) xf[k] = *(const bh8*)(px + k * 32);
  }

  for (int t = 0; t < TT; ++t) {
    if (t > wmax) break;                        // group drained: exit

    // ---- input GEMM first: needs only xf + LDS (off the sync critical path)
    f32x4 acc0 = {bs0, bs0, bs0, bs0};
    f32x4 acc1 = {bs1, bs1, bs1, bs1};
    #pragma unroll
    for (int k = 0; k < 8; ++k) {
      const u32 o = ((u32)(k * 64 + grp * 16)) ^ swz;
      bh8 b0 = *(const bh8*)(pWih0 + o);
      bh8 b1 = *(const bh8*)(pWih1 + o);
      acc0 = __builtin_amdgcn_mfma_f32_16x16x32_bf16(xf[k], b0, acc0, 0, 0, 0);
      acc1 = __builtin_amdgcn_mfma_f32_16x16x32_bf16(xf[k], b1, acc1, 0, 0, 0);
    }

    // ---- wait for step-t h to be published by all 64 WGs of this group
    if (t > 0) {
      u32 v;
      do {
        v = __hip_atomic_load(pf, __ATOMIC_RELAXED, __HIP_MEMORY_SCOPE_AGENT);
      } while (v < (u32)t);
      asm volatile("" ::: "memory");            // no hoisting of h loads
    }

    // ---- h A-fragments
    const u16* ph = (CACHED ? hbuf + (size_t)t * BBHH
                            : hbuf + (size_t)(t & 1) * BBHH)
                    + (size_t)arow * HH + grp * 8;
    bh8 hf[16];
    if (CACHED) {
      #pragma unroll
      for (int k = 0; k < 16; ++k) hf[k] = *(const bh8*)(ph + k * 32);
    } else {
      #pragma unroll
      for (int k = 0; k < 16; ++k) {
        const u16* pk = ph + k * 32;
        asm volatile("global_load_dwordx4 %0, %1, off sc0 sc1"
                     : "=v"(hf[k]) : "v"(pk) : "memory");
      }
    }

    // ---- prefetch xe for t+1 (overwrites xf: input GEMM already consumed it)
    {
      const int tn = (t + 1 < TT) ? t + 1 : t;
      const u16* px = xe + ((size_t)tn * BB + arow) * EE + grp * 8;
      #pragma unroll
      for (int k = 0; k < 8; ++k) xf[k] = *(const bh8*)(px + k * 32);
    }

    if (!CACHED) {
      asm volatile("s_waitcnt vmcnt(0)" ::: "memory");
      __builtin_amdgcn_sched_barrier(0);
    }

    // ---- recurrent GEMM
    #pragma unroll
    for (int k = 0; k < 16; ++k) {
      const u32 o = ((u32)(k * 64 + grp * 16)) ^ swz;
      bh8 b0 = *(const bh8*)(pWhh0 + o);
      bh8 b1 = *(const bh8*)(pWhh1 + o);
      acc0 = __builtin_amdgcn_mfma_f32_16x16x32_bf16(hf[k], b0, acc0, 0, 0, 0);
      acc1 = __builtin_amdgcn_mfma_f32_16x16x32_bf16(hf[k], b1, acc1, 0, 0, 0);
    }

    // ---- epilogue: C row = grp*4+r (batch), col = n16 (gate unit)
    u16* hw = CACHED ? hbuf + (size_t)(t + 1) * BBHH
                     : hbuf + (size_t)((t & 1) ^ 1) * BBHH;
    #pragma unroll
    for (int r = 0; r < 4; ++r) {
      const float v0 = acc0[r];                 // i (n16<8) / f (n16>=8)
      const float v1 = acc1[r];                 // g / o
      const float fv = __shfl_xor(v0, 8);
      const float ov = __shfl_xor(v1, 8);
      const float iv = sigm(v0);
      const float ff = sigm(fv);
      const float gv = tanh_f(v1);
      const float oo = sigm(ov);
      const float cn = ff * cst[r] + iv * gv;
      const float hn = oo * tanh_f(cn);
      const bool valid = (t < lenr[r]);         // packed-seq freeze
      cst[r] = valid ? cn : cst[r];
      hst[r] = valid ? hn : hst[r];
      u32 hv = (u32)f2b(hst[r]);
      u32 up = __shfl_xor(hv, 1);
      // CACHED: store only live rows (frozen rows' bytes are never consumed).
      // parity: store through t==len so both parity buffers hold frozen h.
      const bool dost = CACHED ? valid : (t <= lenr[r]);
      if (((n16 & 1) == 0) && (n16 < 8) && dost)
        __hip_atomic_store((u32*)(hw + (size_t)mrow[r] * HH + wg * 8 + n16),
                           hv | (up << 16), __ATOMIC_RELAXED, __HIP_MEMORY_SCOPE_AGENT);
    }

    // ---- release: write-through stores ack'd at IF -> publish flag
    asm volatile("s_waitcnt vmcnt(0)" ::: "memory");
    if (lane == 0)
      __hip_atomic_store(myf, (u32)(t + 1), __ATOMIC_RELAXED, __HIP_MEMORY_SCOPE_AGENT);
  }

  // drained: park flag past the horizon so nobody ever waits on this wave
  asm volatile("s_waitcnt vmcnt(0)" ::: "memory");
  if (lane == 0)
    __hip_atomic_store(myf, (u32)(TT + 1), __ATOMIC_RELAXED, __HIP_MEMORY_SCOPE_AGENT);
}

// ---- kernel 3: out[b] = sigmoid(h_last[b] . fc_w + fc_b) ----
// mode 1 (cached): row b's final h lives in hbuf[len[b]]. mode 0: buffer 0.
__global__ __launch_bounds__(64) void k_fc(const u16* __restrict__ hbuf,
    const int* __restrict__ xlen, const float* __restrict__ fcw,
    const float* __restrict__ fcb, float* __restrict__ out, int mode)
{
  const int b = blockIdx.x;
  const int lane = threadIdx.x;
  const u16* hr = hbuf + (mode ? (size_t)xlen[b] * BBHH : (size_t)0) + (size_t)b * HH;
  float s = 0.f;
  #pragma unroll
  for (int j = 0; j < 8; ++j) {
    const int u = lane + j * 64;
    s += b2f(hr[u]) * fcw[u];
  }
  #pragma unroll
  for (int off = 32; off > 0; off >>= 1) s += __shfl_xor(s, off);
  if (lane == 0) out[b] = sigm(s + fcb[0]);
}

extern "C" void kernel_launch(void* const* d_in, const int* in_sizes, int n_in,
                              void* d_out, int out_size, void* d_ws, size_t ws_size,
                              hipStream_t stream)
{
  const int*   x    = (const int*)  d_in[0];
  const int*   xlen = (const int*)  d_in[1];
  const float* emb  = (const float*)d_in[2];
  const float* Wih  = (const float*)d_in[3];
  const float* Whh  = (const float*)d_in[4];
  const float* bih  = (const float*)d_in[5];
  const float* bhh  = (const float*)d_in[6];
  const float* fcw  = (const float*)d_in[7];
  const float* fcb  = (const float*)d_in[8];
  float* out = (float*)d_out;

  char* ws = (char*)d_ws;
  u32* flags = (u32*)ws;                                   // 4 KB slot
  u16* xe    = (u16*)(ws + 4096);                          // 16 MB
  u16* hbuf  = (u16*)(ws + 4096 + (size_t)TT * BB * EE * 2);

  // cached path needs 4KB + 16MB + 513*64KB = 50,401,280 B of ws
  const bool cached = (ws_size >= (size_t)50401280);

  k_init <<<dim3(128), dim3(256), 0, stream>>>(flags, (u32*)hbuf);
  k_embed<<<dim3((TT * BB * EE / 8) / 256), dim3(256), 0, stream>>>(x, emb, xe);
  if (cached) {
    k_lstm<true> <<<dim3(NWG), dim3(THREADS), 0, stream>>>(Whh, Wih, bih, bhh, xe, xlen, hbuf, flags);
    k_fc<<<dim3(BB), dim3(64), 0, stream>>>(hbuf, xlen, fcw, fcb, out, 1);
  } else {
    k_lstm<false><<<dim3(NWG), dim3(THREADS), 0, stream>>>(Whh, Wih, bih, bhh, xe, xlen, hbuf, flags);
    k_fc<<<dim3(BB), dim3(64), 0, stream>>>(hbuf, xlen, fcw, fcb, out, 0);
  }
}